// Round 1
// baseline (50078.699 us; speedup 1.0000x reference)
//
#include <hip/hip_runtime.h>
#include <math.h>

#define T_DIM 512
#define B_DIM 64
#define I_DIM 1024
#define H_DIM 1024

// d_out layout (flat f32): ys [T][B][2H], hT_f [B][H], cT_f, hT_b, cT_b
#define OUT_HTF (T_DIM * B_DIM * 2 * H_DIM)
#define OUT_CTF (OUT_HTF + B_DIM * H_DIM)
#define OUT_HTB (OUT_CTF + B_DIM * H_DIM)
#define OUT_CTB (OUT_HTB + B_DIM * H_DIM)

__device__ __forceinline__ float sigmoidf_(float v) {
    return 1.0f / (1.0f + expf(-v));
}

// One time-step for BOTH directions.
// Grid: 256 blocks x 256 threads. Block b: dir = b>>7, u0 = (b&127)*8.
// Block computes gates[64 batch][32 cols] where the 32 cols are
// {i,f,g,o} x 8 units (u0..u0+7), K = 2048 fused (x then h), then does the
// elementwise c/h update for its 8 units (block-local since all 4 gates here).
__global__ __launch_bounds__(256) void lstm_step(
    const float* __restrict__ x,
    const float* __restrict__ h0f, const float* __restrict__ c0f,
    const float* __restrict__ h0b, const float* __restrict__ c0b,
    const float* __restrict__ wihf, const float* __restrict__ whhf,
    const float* __restrict__ bihf, const float* __restrict__ bhhf,
    const float* __restrict__ wihb, const float* __restrict__ whhb,
    const float* __restrict__ bihb, const float* __restrict__ bhhb,
    float* __restrict__ out, int step)
{
    // 2 x [64 m][128 k] A-panel chunks, XOR-swizzled, 64 KB total
    __shared__ float smem[2 * 64 * 128];

    const int tid = threadIdx.x;
    const int bid = blockIdx.x;
    const int dir = bid >> 7;            // 0 = fwd, 1 = bwd
    const int u0  = (bid & 127) * 8;     // hidden-unit base
    const int t   = dir ? (T_DIM - 1 - step) : step;

    const float* w_ih = dir ? wihb : wihf;
    const float* w_hh = dir ? whhb : whhf;
    const float* xt   = x + (size_t)t * B_DIM * I_DIM;

    // h_{t-1} source: initial state at step 0, else previously-written out slice
    const float* hprev;
    int hst;
    if (step == 0) {
        hprev = dir ? h0b : h0f;
        hst = H_DIM;
    } else {
        const int tprev = dir ? (t + 1) : (t - 1);
        hprev = out + (size_t)tprev * B_DIM * 2 * H_DIM + dir * H_DIM;
        hst = 2 * H_DIM;
    }

    // ---- GEMM thread mapping: thread tile = 4 rows (m) x 2 cols (j, j+1) ----
    const int jp = tid >> 4;             // 0..15 -> column pair
    const int mg = tid & 15;             // m-group -> rows mg*4 .. mg*4+3
    const int c0 = jp * 2;               // block-local col 0..30 (even)
    // col c -> j = gate*H + u0 + (c&7); c0 even => j1 = j0 + 1 (same gate)
    const int j0 = (c0 >> 3) * H_DIM + u0 + (c0 & 7);

    float acc[4][2];
#pragma unroll
    for (int i = 0; i < 4; ++i) { acc[i][0] = 0.f; acc[i][1] = 0.f; }

    float4 ld[8];  // register staging for the next K-chunk

    auto issue_loads = [&](int kc) {
        const bool isX = (kc < 8);
        const float* src = isX ? xt : hprev;
        const int stride = isX ? I_DIM : hst;
        const int kb = (isX ? kc : (kc - 8)) * 128;
#pragma unroll
        for (int p = 0; p < 8; ++p) {
            const int e = p * 256 + tid;         // 0..2047
            const int m = e >> 5;                // 0..63
            const int q = e & 31;                // float4 group 0..31
            ld[p] = *reinterpret_cast<const float4*>(
                src + (size_t)m * stride + kb + q * 4);
        }
    };

    auto write_smem = [&](int buf) {
        float* dst = smem + buf * 8192;
#pragma unroll
        for (int p = 0; p < 8; ++p) {
            const int e = p * 256 + tid;
            const int m = e >> 5;
            const int q = e & 31;
            const int qs = q ^ ((m >> 2) & 7);   // bank swizzle
            *reinterpret_cast<float4*>(&dst[m * 128 + qs * 4]) = ld[p];
        }
    };

    auto compute = [&](int kc, int buf) {
        const bool isX = (kc < 8);
        const int kb = (isX ? kc : (kc - 8)) * 128;
        const float* wp0 = (isX ? w_ih : w_hh) + (size_t)j0 * 1024 + kb;
        const float* wp1 = wp0 + 1024;           // j0+1 row
        const float* sb = smem + buf * 8192 + (mg * 4) * 128;
#pragma unroll 4
        for (int q = 0; q < 32; ++q) {
            const float4 w0 = *reinterpret_cast<const float4*>(wp0 + q * 4);
            const float4 w1 = *reinterpret_cast<const float4*>(wp1 + q * 4);
            const int qs = (q ^ (mg & 7)) * 4;
#pragma unroll
            for (int i = 0; i < 4; ++i) {
                const float4 a =
                    *reinterpret_cast<const float4*>(&sb[i * 128 + qs]);
                acc[i][0] = fmaf(a.x, w0.x, fmaf(a.y, w0.y,
                            fmaf(a.z, w0.z, fmaf(a.w, w0.w, acc[i][0]))));
                acc[i][1] = fmaf(a.x, w1.x, fmaf(a.y, w1.y,
                            fmaf(a.z, w1.z, fmaf(a.w, w1.w, acc[i][1]))));
            }
        }
    };

    // ---- K loop: 16 chunks of 128, double-buffered via registers ----
    issue_loads(0);
    write_smem(0);
    __syncthreads();
    for (int kc = 0; kc < 16; ++kc) {
        if (kc < 15) issue_loads(kc + 1);
        compute(kc, kc & 1);
        __syncthreads();
        if (kc < 15) {
            write_smem((kc + 1) & 1);
            __syncthreads();
        }
    }

    // ---- bias + gate exchange through LDS ----
    const float* bih = dir ? bihb : bihf;
    const float* bhh = dir ? bhhb : bhhf;
    const float bb0 = bih[j0] + bhh[j0];
    const float bb1 = bih[j0 + 1] + bhh[j0 + 1];

    // gates layout: [c 0..31][m 0..63], stride 65 (reuse smem buf0 region)
#pragma unroll
    for (int i = 0; i < 4; ++i) {
        const int m = mg * 4 + i;
        smem[c0 * 65 + m]       = acc[i][0] + bb0;
        smem[(c0 + 1) * 65 + m] = acc[i][1] + bb1;
    }
    __syncthreads();

    // ---- elementwise LSTM update: 512 cells (64 b x 8 u), 2 per thread ----
    float* cslot = out + (dir ? OUT_CTB : OUT_CTF);
    float* hslot = out + (dir ? OUT_HTB : OUT_HTF);
    const float* cinit = dir ? c0b : c0f;
#pragma unroll
    for (int s2 = 0; s2 < 2; ++s2) {
        const int cell = s2 * 256 + tid;     // 0..511
        const int du = cell >> 6;            // 0..7
        const int m = cell & 63;
        const int u = u0 + du;
        const float ig = smem[(0 * 8 + du) * 65 + m];
        const float fg = smem[(1 * 8 + du) * 65 + m];
        const float gg = smem[(2 * 8 + du) * 65 + m];
        const float og = smem[(3 * 8 + du) * 65 + m];
        const float cp = (step == 0) ? cinit[m * H_DIM + u]
                                     : cslot[m * H_DIM + u];
        const float cn = sigmoidf_(fg) * cp + sigmoidf_(ig) * tanhf(gg);
        const float h  = sigmoidf_(og) * tanhf(cn);
        cslot[m * H_DIM + u] = cn;
        out[(size_t)t * B_DIM * 2 * H_DIM + m * 2 * H_DIM + dir * H_DIM + u] = h;
        if (step == T_DIM - 1) hslot[m * H_DIM + u] = h;
    }
}

extern "C" void kernel_launch(void* const* d_in, const int* in_sizes, int n_in,
                              void* d_out, int out_size, void* d_ws, size_t ws_size,
                              hipStream_t stream)
{
    const float* x    = (const float*)d_in[0];
    const float* h0f  = (const float*)d_in[1];
    const float* c0f  = (const float*)d_in[2];
    const float* h0b  = (const float*)d_in[3];
    const float* c0b  = (const float*)d_in[4];
    const float* wihf = (const float*)d_in[5];
    const float* whhf = (const float*)d_in[6];
    const float* bihf = (const float*)d_in[7];
    const float* bhhf = (const float*)d_in[8];
    const float* wihb = (const float*)d_in[9];
    const float* whhb = (const float*)d_in[10];
    const float* bihb = (const float*)d_in[11];
    const float* bhhb = (const float*)d_in[12];
    float* out = (float*)d_out;

    for (int s = 0; s < T_DIM; ++s) {
        lstm_step<<<dim3(256), dim3(256), 0, stream>>>(
            x, h0f, c0f, h0b, c0b,
            wihf, whhf, bihf, bhhf,
            wihb, whhb, bihb, bhhb,
            out, s);
    }
}